// Round 3
// baseline (540.744 us; speedup 1.0000x reference)
//
#include <hip/hip_runtime.h>
#include <hip/hip_bf16.h>

#define EDGE_DIM 64
#define UPD 256

typedef __attribute__((ext_vector_type(8))) short bf16x8;
typedef __attribute__((ext_vector_type(4))) float f32x4;

__device__ __forceinline__ short f2bf(float v) {
    __hip_bfloat16 b = __float2bfloat16(v);
    return *(short*)&b;
}
__device__ __forceinline__ float bf2f(short s) {
    __hip_bfloat16 b = *(__hip_bfloat16*)&s;
    return __bfloat162float(b);
}

// ---------------------------------------------------------------------------
// Kernel 0: detect int64 vs int32 idx (flag=1 -> int64).
// ---------------------------------------------------------------------------
__global__ void detect_idx_kernel(const void* __restrict__ idx, int n_edge,
                                  int num_nodes, int* __restrict__ flag) {
    if (threadIdx.x == 0) *flag = 1;
    __syncthreads();
    const long long* p = (const long long*)idx;
    int nchk = n_edge < 1024 ? n_edge : 1024;
    for (int i = threadIdx.x; i < nchk; i += blockDim.x) {
        long long v = p[i];
        if (v < 0 || v >= (long long)num_nodes) atomicExch(flag, 0);
    }
}

// ---------------------------------------------------------------------------
// Counting sort phase A: per-node histogram.
// ---------------------------------------------------------------------------
__global__ __launch_bounds__(256) void count_kernel(
    const void* __restrict__ idx_v, const int* __restrict__ flag, int n_edge,
    int* __restrict__ count) {
    const int use64 = *flag;
    const long long* i64 = (const long long*)idx_v;
    const int* i32 = (const int*)idx_v;
    for (int e = blockIdx.x * blockDim.x + threadIdx.x; e < n_edge;
         e += gridDim.x * blockDim.x) {
        int n = use64 ? (int)i64[e] : i32[e];
        atomicAdd(&count[n], 1);
    }
}

// ---------------------------------------------------------------------------
// Scan: 3-kernel exclusive prefix over count[nn] -> base[nn+1].
// scan_a: block b handles 1024 elems; local exclusive scan -> base,
//         block total -> partial[b].
// ---------------------------------------------------------------------------
__global__ __launch_bounds__(256) void scan_a(const int* __restrict__ count,
                                              int* __restrict__ base,
                                              int* __restrict__ partial,
                                              int nn) {
    __shared__ int s[256];
    const int tid = threadIdx.x;
    const int i0 = blockIdx.x * 1024 + tid * 4;
    int c[4], tsum = 0;
#pragma unroll
    for (int j = 0; j < 4; ++j) {
        c[j] = (i0 + j < nn) ? count[i0 + j] : 0;
        tsum += c[j];
    }
    s[tid] = tsum;
    __syncthreads();
    for (int off = 1; off < 256; off <<= 1) {
        int v = (tid >= off) ? s[tid - off] : 0;
        __syncthreads();
        s[tid] += v;
        __syncthreads();
    }
    int run = s[tid] - tsum;  // exclusive within block
    if (tid == 255) partial[blockIdx.x] = s[255];
#pragma unroll
    for (int j = 0; j < 4; ++j) {
        if (i0 + j < nn) base[i0 + j] = run;
        run += c[j];
    }
}

__global__ __launch_bounds__(256) void scan_b(int* __restrict__ partial,
                                              int nblk) {
    __shared__ int s[256];
    const int tid = threadIdx.x;
    int v = (tid < nblk) ? partial[tid] : 0;
    s[tid] = v;
    __syncthreads();
    for (int off = 1; off < 256; off <<= 1) {
        int u = (tid >= off) ? s[tid - off] : 0;
        __syncthreads();
        s[tid] += u;
        __syncthreads();
    }
    if (tid < nblk) partial[tid] = s[tid] - v;  // exclusive
}

__global__ __launch_bounds__(256) void scan_c(int* __restrict__ base,
                                              int* __restrict__ cursor,
                                              const int* __restrict__ partial,
                                              int nn, int n_edge) {
    const int tid = threadIdx.x;
    const int b = blockIdx.x;
    const int add = partial[b];
    const int i0 = b * 1024 + tid * 4;
#pragma unroll
    for (int j = 0; j < 4; ++j) {
        int i = i0 + j;
        if (i < nn) {
            int v = base[i] + add;
            base[i] = v;
            cursor[i] = v;
        }
    }
    if (b == 0 && tid == 0) base[nn] = n_edge;
}

// ---------------------------------------------------------------------------
// Phase B: scatter edge ids into node-sorted order.
// ---------------------------------------------------------------------------
__global__ __launch_bounds__(256) void fill_order_kernel(
    const void* __restrict__ idx_v, const int* __restrict__ flag, int n_edge,
    int* __restrict__ cursor, int* __restrict__ order) {
    const int use64 = *flag;
    const long long* i64 = (const long long*)idx_v;
    const int* i32 = (const int*)idx_v;
    for (int e = blockIdx.x * blockDim.x + threadIdx.x; e < n_edge;
         e += gridDim.x * blockDim.x) {
        int n = use64 ? (int)i64[e] : i32[e];
        int p = atomicAdd(&cursor[n], 1);
        order[p] = e;
    }
}

// ---------------------------------------------------------------------------
// Phase C: per-node gather-reduce. One wave per node; lane = feature dim.
// h[n][d] = sum_{e in node n} (rbf[e] @ Wrbf)[d] * x[e][d]
// ---------------------------------------------------------------------------
__global__ __launch_bounds__(256) void gather_kernel(
    const float* __restrict__ x, const float* __restrict__ rbf,
    const int* __restrict__ order, const int* __restrict__ base,
    const float* __restrict__ Wrbf, float* __restrict__ h, int nn) {
    __shared__ float w[16 * EDGE_DIM];
    for (int i = threadIdx.x; i < 16 * EDGE_DIM; i += blockDim.x)
        w[i] = Wrbf[i];
    __syncthreads();

    const int lane = threadIdx.x & 63;
    const int wid = threadIdx.x >> 6;
    const int gw = blockIdx.x * 4 + wid;
    const int nwaves = gridDim.x * 4;

    for (int n = gw; n < nn; n += nwaves) {
        const int b0 = base[n], b1 = base[n + 1];
        float acc = 0.f;
        for (int i0 = b0; i0 < b1; i0 += 64) {
            const int m = min(64, b1 - i0);
            int e_l = (lane < m) ? order[i0 + lane] : 0;
            for (int i = 0; i < m; ++i) {
                int e = __shfl(e_l, i);
                float r = rbf[(long long)e * 16 + (lane & 15)];
                float xv = x[(long long)e * EDGE_DIM + lane];
                float s = 0.f;
#pragma unroll
                for (int q = 0; q < 16; ++q)
                    s = fmaf(__shfl(r, q), w[q * EDGE_DIM + lane], s);
                acc = fmaf(s, xv, acc);
            }
        }
        h[(long long)n * EDGE_DIM + lane] = acc;
    }
}

// ---------------------------------------------------------------------------
// Pack weight matrix W [K][256] f32 into MFMA-fragment order, bf16 hi/lo.
// ---------------------------------------------------------------------------
__global__ void pack_w_kernel(const float* __restrict__ W,
                              short* __restrict__ out, int K) {
    int t = blockIdx.x * blockDim.x + threadIdx.x;
    int nfrag = (K / 32) * 16;
    if (t >= nfrag * 64) return;
    int l = t & 63, f = t >> 6;
    int kt = f >> 4, nt = f & 15;
    int kbase = kt * 32 + (l >> 4) * 8;
    int col = nt * 16 + (l & 15);
#pragma unroll
    for (int j = 0; j < 8; ++j) {
        float v = W[(kbase + j) * UPD + col];
        short hb = f2bf(v);
        short lb = f2bf(v - bf2f(hb));
        out[f * 1024 + l * 8 + j] = hb;
        out[f * 1024 + 512 + l * 8 + j] = lb;
    }
}

// ---------------------------------------------------------------------------
// MFMA node MLP (unchanged from R2).
// ---------------------------------------------------------------------------
template <int NK>
__device__ __forceinline__ void mm_layer(const short* AH, const short* AL,
                                         const short* __restrict__ Wpk,
                                         int lr, int lh, int lane, int wq,
                                         f32x4 acc[4][4]) {
#pragma unroll
    for (int kt = 0; kt < NK; ++kt) {
        bf16x8 a[4][2];
#pragma unroll
        for (int m = 0; m < 4; ++m) {
            int r = m * 16 + lr;
            int ch = (kt * 4 + lh) ^ (r & 7);
            int off = r * 256 + ch * 8;  // shorts
            a[m][0] = *(const bf16x8*)(AH + off);
            a[m][1] = *(const bf16x8*)(AL + off);
        }
        bf16x8 b[4][2];
#pragma unroll
        for (int nf = 0; nf < 4; ++nf) {
            int f = kt * 16 + wq * 4 + nf;
            const short* p = Wpk + f * 1024 + lane * 8;
            b[nf][0] = *(const bf16x8*)(p);
            b[nf][1] = *(const bf16x8*)(p + 512);
        }
#pragma unroll
        for (int m = 0; m < 4; ++m)
#pragma unroll
            for (int nf = 0; nf < 4; ++nf) {
                acc[m][nf] = __builtin_amdgcn_mfma_f32_16x16x32_bf16(
                    a[m][0], b[nf][0], acc[m][nf], 0, 0, 0);
                acc[m][nf] = __builtin_amdgcn_mfma_f32_16x16x32_bf16(
                    a[m][0], b[nf][1], acc[m][nf], 0, 0, 0);
                acc[m][nf] = __builtin_amdgcn_mfma_f32_16x16x32_bf16(
                    a[m][1], b[nf][0], acc[m][nf], 0, 0, 0);
            }
    }
}

template <bool ACT>
__device__ __forceinline__ void epilogue_store(f32x4 acc[4][4], short* AH,
                                               short* AL,
                                               const float* __restrict__ bias,
                                               int lr, int lh, int wq) {
    float bv[4] = {0.f, 0.f, 0.f, 0.f};
    if (bias) {
#pragma unroll
        for (int nf = 0; nf < 4; ++nf) bv[nf] = bias[wq * 64 + nf * 16 + lr];
    }
#pragma unroll
    for (int m = 0; m < 4; ++m)
#pragma unroll
        for (int nf = 0; nf < 4; ++nf) {
            int c = wq * 64 + nf * 16 + lr;
#pragma unroll
            for (int reg = 0; reg < 4; ++reg) {
                float v = acc[m][nf][reg] + bv[nf];
                if (ACT) v = v / (1.f + __expf(-v));
                int r = m * 16 + lh * 4 + reg;
                short hb = f2bf(v);
                short lb = f2bf(v - bf2f(hb));
                int off = r * 256 + (((c >> 3) ^ (r & 7)) * 8) + (c & 7);
                AH[off] = hb;
                AL[off] = lb;
            }
        }
}

__global__ __launch_bounds__(256, 2) void node_mlp_mfma(
    const float* __restrict__ h,
    const short* __restrict__ Wup_pk, const short* __restrict__ W1_pk,
    const short* __restrict__ W2_pk, const short* __restrict__ W3_pk,
    const float* __restrict__ b1, const float* __restrict__ b2,
    const float* __restrict__ b3, const float* __restrict__ W_out,
    float* __restrict__ out, int nn) {
    __shared__ short AH[64 * 256];
    __shared__ short AL[64 * 256];
    __shared__ float Bpart[64 * 4];

    const int tid = threadIdx.x;
    const int lane = tid & 63, wq = tid >> 6;
    const int lr = lane & 15, lh = lane >> 4;
    const int node0 = blockIdx.x * 64;

    // Stage h tile (64 x 64 f32) -> hi/lo bf16, swizzled, cols 0..63.
#pragma unroll
    for (int i = 0; i < 4; ++i) {
        int idx4 = tid + i * 256;  // 0..1023 float4s
        int r = idx4 >> 4, c4 = idx4 & 15;
        float4 v = {0.f, 0.f, 0.f, 0.f};
        if (node0 + r < nn)
            v = *(const float4*)(h + (long long)(node0 + r) * EDGE_DIM + c4 * 4);
        short h0 = f2bf(v.x), h1 = f2bf(v.y), h2 = f2bf(v.z), h3 = f2bf(v.w);
        short l0 = f2bf(v.x - bf2f(h0)), l1 = f2bf(v.y - bf2f(h1));
        short l2 = f2bf(v.z - bf2f(h2)), l3 = f2bf(v.w - bf2f(h3));
        int off = r * 256 + (((c4 >> 1) ^ (r & 7)) * 8) + (c4 & 1) * 4;
        uint2 hw, lw;
        hw.x = (unsigned short)h0 | ((unsigned)(unsigned short)h1 << 16);
        hw.y = (unsigned short)h2 | ((unsigned)(unsigned short)h3 << 16);
        lw.x = (unsigned short)l0 | ((unsigned)(unsigned short)l1 << 16);
        lw.y = (unsigned short)l2 | ((unsigned)(unsigned short)l3 << 16);
        *(uint2*)(AH + off) = hw;
        *(uint2*)(AL + off) = lw;
    }
    __syncthreads();

    f32x4 acc[4][4];

    // Layer up: K=64, no bias, no act.
#pragma unroll
    for (int m = 0; m < 4; ++m)
#pragma unroll
        for (int n = 0; n < 4; ++n) acc[m][n] = (f32x4){0.f, 0.f, 0.f, 0.f};
    mm_layer<2>(AH, AL, Wup_pk, lr, lh, lane, wq, acc);
    __syncthreads();
    epilogue_store<false>(acc, AH, AL, nullptr, lr, lh, wq);
    __syncthreads();

    // Layer 1
#pragma unroll
    for (int m = 0; m < 4; ++m)
#pragma unroll
        for (int n = 0; n < 4; ++n) acc[m][n] = (f32x4){0.f, 0.f, 0.f, 0.f};
    mm_layer<8>(AH, AL, W1_pk, lr, lh, lane, wq, acc);
    __syncthreads();
    epilogue_store<true>(acc, AH, AL, b1, lr, lh, wq);
    __syncthreads();

    // Layer 2
#pragma unroll
    for (int m = 0; m < 4; ++m)
#pragma unroll
        for (int n = 0; n < 4; ++n) acc[m][n] = (f32x4){0.f, 0.f, 0.f, 0.f};
    mm_layer<8>(AH, AL, W2_pk, lr, lh, lane, wq, acc);
    __syncthreads();
    epilogue_store<true>(acc, AH, AL, b2, lr, lh, wq);
    __syncthreads();

    // Layer 3 + fused head: out = silu(acc + b3) . W_out
#pragma unroll
    for (int m = 0; m < 4; ++m)
#pragma unroll
        for (int n = 0; n < 4; ++n) acc[m][n] = (f32x4){0.f, 0.f, 0.f, 0.f};
    mm_layer<8>(AH, AL, W3_pk, lr, lh, lane, wq, acc);

    float b3v[4], wo[4];
#pragma unroll
    for (int nf = 0; nf < 4; ++nf) {
        int c = wq * 64 + nf * 16 + lr;
        b3v[nf] = b3[c];
        wo[nf] = W_out[c];
    }
#pragma unroll
    for (int m = 0; m < 4; ++m) {
#pragma unroll
        for (int reg = 0; reg < 4; ++reg) {
            float s = 0.f;
#pragma unroll
            for (int nf = 0; nf < 4; ++nf) {
                float v = acc[m][nf][reg] + b3v[nf];
                v = v / (1.f + __expf(-v));
                s = fmaf(v, wo[nf], s);
            }
            s += __shfl_xor(s, 1);
            s += __shfl_xor(s, 2);
            s += __shfl_xor(s, 4);
            s += __shfl_xor(s, 8);
            if (lr == 0) Bpart[(m * 16 + lh * 4 + reg) * 4 + wq] = s;
        }
    }
    __syncthreads();
    if (tid < 64) {
        float s = Bpart[tid * 4] + Bpart[tid * 4 + 1] + Bpart[tid * 4 + 2] +
                  Bpart[tid * 4 + 3];
        if (node0 + tid < nn) out[node0 + tid] = s;
    }
}

// ---------------------------------------------------------------------------
extern "C" void kernel_launch(void* const* d_in, const int* in_sizes, int n_in,
                              void* d_out, int out_size, void* d_ws, size_t ws_size,
                              hipStream_t stream) {
    const float* x     = (const float*)d_in[0];
    const float* rbf   = (const float*)d_in[1];
    const void*  idx   = d_in[2];
    const float* W_rbf = (const float*)d_in[4];
    const float* W_up  = (const float*)d_in[5];
    const float* W1    = (const float*)d_in[6];
    const float* b1    = (const float*)d_in[7];
    const float* W2    = (const float*)d_in[8];
    const float* b2    = (const float*)d_in[9];
    const float* W3    = (const float*)d_in[10];
    const float* b3    = (const float*)d_in[11];
    const float* W_out = (const float*)d_in[12];
    float* out = (float*)d_out;

    const int n_edge = in_sizes[0] / EDGE_DIM;
    const int nn = out_size;

    // Workspace layout
    char* p = (char*)d_ws;
    float* h = (float*)p;            p += (size_t)nn * EDGE_DIM * sizeof(float);
    short* wup_pk = (short*)p;       p += 32 * 1024 * sizeof(short);
    short* w1_pk = (short*)p;        p += 128 * 1024 * sizeof(short);
    short* w2_pk = (short*)p;        p += 128 * 1024 * sizeof(short);
    short* w3_pk = (short*)p;        p += 128 * 1024 * sizeof(short);
    int* count = (int*)p;            p += (size_t)nn * sizeof(int);
    int* base = (int*)p;             p += (size_t)(nn + 1) * sizeof(int);
    int* cursor = (int*)p;           p += (size_t)nn * sizeof(int);
    int* partial = (int*)p;          p += 256 * sizeof(int);
    int* order = (int*)p;            p += (size_t)n_edge * sizeof(int);
    int* flag = (int*)p;

    const int nblk_scan = (nn + 1023) / 1024;

    hipMemsetAsync(count, 0, (size_t)nn * sizeof(int), stream);
    detect_idx_kernel<<<1, 256, 0, stream>>>(idx, n_edge, nn, flag);

    // weight packing (independent of edge phase, same stream)
    pack_w_kernel<<<8, 256, 0, stream>>>(W_up, wup_pk, 64);
    pack_w_kernel<<<32, 256, 0, stream>>>(W1, w1_pk, 256);
    pack_w_kernel<<<32, 256, 0, stream>>>(W2, w2_pk, 256);
    pack_w_kernel<<<32, 256, 0, stream>>>(W3, w3_pk, 256);

    // counting sort
    count_kernel<<<2048, 256, 0, stream>>>(idx, flag, n_edge, count);
    scan_a<<<nblk_scan, 256, 0, stream>>>(count, base, partial, nn);
    scan_b<<<1, 256, 0, stream>>>(partial, nblk_scan);
    scan_c<<<nblk_scan, 256, 0, stream>>>(base, cursor, partial, nn, n_edge);
    fill_order_kernel<<<2048, 256, 0, stream>>>(idx, flag, n_edge, cursor,
                                                order);
    // gather-reduce
    gather_kernel<<<2048, 256, 0, stream>>>(x, rbf, order, base, W_rbf, h, nn);

    const int nb = (nn + 63) / 64;
    node_mlp_mfma<<<nb, 256, 0, stream>>>(h, wup_pk, w1_pk, w2_pk, w3_pk,
                                          b1, b2, b3, W_out, out, nn);
}

// Round 4
// 389.729 us; speedup vs baseline: 1.3875x; 1.3875x over previous
//
#include <hip/hip_runtime.h>
#include <hip/hip_bf16.h>

#define EDGE_DIM 64
#define UPD 256

typedef __attribute__((ext_vector_type(8))) short bf16x8;
typedef __attribute__((ext_vector_type(4))) float f32x4;

__device__ __forceinline__ short f2bf(float v) {
    __hip_bfloat16 b = __float2bfloat16(v);
    return *(short*)&b;
}
__device__ __forceinline__ float bf2f(short s) {
    __hip_bfloat16 b = *(__hip_bfloat16*)&s;
    return __bfloat162float(b);
}

// ---------------------------------------------------------------------------
// Per-block idx-dtype detection (deterministic, every block gets same answer).
// Returns 1 if idx is int64, 0 if int32.
// ---------------------------------------------------------------------------
__device__ __forceinline__ int detect_use64_block(const void* idx_v,
                                                  int n_edge, int nn,
                                                  int* bad_s) {
    if (threadIdx.x == 0) *bad_s = 0;
    __syncthreads();
    const long long* p = (const long long*)idx_v;
    int i = threadIdx.x;
    if (i < 256 && i < n_edge) {
        long long v = p[i];
        if (v < 0 || v >= (long long)nn) *bad_s = 1;  // benign race
    }
    __syncthreads();
    return !(*bad_s);
}

// ---------------------------------------------------------------------------
// Counting sort phase A: per-node histogram (idx detect fused).
// ---------------------------------------------------------------------------
__global__ __launch_bounds__(256) void count_kernel(
    const void* __restrict__ idx_v, int n_edge, int nn,
    int* __restrict__ count) {
    __shared__ int bad_s;
    const int use64 = detect_use64_block(idx_v, n_edge, nn, &bad_s);
    const long long* i64 = (const long long*)idx_v;
    const int* i32 = (const int*)idx_v;
    for (int e = blockIdx.x * blockDim.x + threadIdx.x; e < n_edge;
         e += gridDim.x * blockDim.x) {
        int n = use64 ? (int)i64[e] : i32[e];
        atomicAdd(&count[n], 1);
    }
}

// ---------------------------------------------------------------------------
// Scan: 3-kernel exclusive prefix over count[nn] -> base[nn+1].
// ---------------------------------------------------------------------------
__global__ __launch_bounds__(256) void scan_a(const int* __restrict__ count,
                                              int* __restrict__ base,
                                              int* __restrict__ partial,
                                              int nn) {
    __shared__ int s[256];
    const int tid = threadIdx.x;
    const int i0 = blockIdx.x * 1024 + tid * 4;
    int c[4], tsum = 0;
#pragma unroll
    for (int j = 0; j < 4; ++j) {
        c[j] = (i0 + j < nn) ? count[i0 + j] : 0;
        tsum += c[j];
    }
    s[tid] = tsum;
    __syncthreads();
    for (int off = 1; off < 256; off <<= 1) {
        int v = (tid >= off) ? s[tid - off] : 0;
        __syncthreads();
        s[tid] += v;
        __syncthreads();
    }
    int run = s[tid] - tsum;  // exclusive within block
    if (tid == 255) partial[blockIdx.x] = s[255];
#pragma unroll
    for (int j = 0; j < 4; ++j) {
        if (i0 + j < nn) base[i0 + j] = run;
        run += c[j];
    }
}

__global__ __launch_bounds__(256) void scan_b(int* __restrict__ partial,
                                              int nblk) {
    __shared__ int s[256];
    const int tid = threadIdx.x;
    int v = (tid < nblk) ? partial[tid] : 0;
    s[tid] = v;
    __syncthreads();
    for (int off = 1; off < 256; off <<= 1) {
        int u = (tid >= off) ? s[tid - off] : 0;
        __syncthreads();
        s[tid] += u;
        __syncthreads();
    }
    if (tid < nblk) partial[tid] = s[tid] - v;  // exclusive
}

__global__ __launch_bounds__(256) void scan_c(int* __restrict__ base,
                                              int* __restrict__ cursor,
                                              const int* __restrict__ partial,
                                              int nn, int n_edge) {
    const int tid = threadIdx.x;
    const int b = blockIdx.x;
    const int add = partial[b];
    const int i0 = b * 1024 + tid * 4;
#pragma unroll
    for (int j = 0; j < 4; ++j) {
        int i = i0 + j;
        if (i < nn) {
            int v = base[i] + add;
            base[i] = v;
            cursor[i] = v;
        }
    }
    if (b == 0 && tid == 0) base[nn] = n_edge;
}

// ---------------------------------------------------------------------------
// Phase B: scatter edge ids into node-sorted order (idx detect fused).
// ---------------------------------------------------------------------------
__global__ __launch_bounds__(256) void fill_order_kernel(
    const void* __restrict__ idx_v, int n_edge, int nn,
    int* __restrict__ cursor, int* __restrict__ order) {
    __shared__ int bad_s;
    const int use64 = detect_use64_block(idx_v, n_edge, nn, &bad_s);
    const long long* i64 = (const long long*)idx_v;
    const int* i32 = (const int*)idx_v;
    for (int e = blockIdx.x * blockDim.x + threadIdx.x; e < n_edge;
         e += gridDim.x * blockDim.x) {
        int n = use64 ? (int)i64[e] : i32[e];
        int p = atomicAdd(&cursor[n], 1);
        order[p] = e;
    }
}

// ---------------------------------------------------------------------------
// Phase C: per-node gather-reduce, scalarized walk + 4-edge unroll.
// Wave-uniform node id -> base/order/rbf come in via scalar loads; the
// W_rbf column for this lane lives in 16 VGPRs; zero LDS ops in the loop.
// ---------------------------------------------------------------------------
__global__ __launch_bounds__(256) void gather_kernel(
    const float* __restrict__ x, const float* __restrict__ rbf,
    const int* __restrict__ order, const int* __restrict__ base,
    const float* __restrict__ Wrbf, float* __restrict__ h, int nn) {
    const int lane = threadIdx.x & 63;
    float wreg[16];
#pragma unroll
    for (int q = 0; q < 16; ++q) wreg[q] = Wrbf[q * EDGE_DIM + lane];

    const int wid = __builtin_amdgcn_readfirstlane(threadIdx.x >> 6);
    const int gw = blockIdx.x * 4 + wid;
    const int nwaves = gridDim.x * 4;

    for (int n = gw; n < nn; n += nwaves) {
        const int b0 = base[n], b1 = base[n + 1];
        float acc = 0.f;
        int i = b0;
        for (; i + 4 <= b1; i += 4) {
            const int e0 = order[i + 0];
            const int e1 = order[i + 1];
            const int e2 = order[i + 2];
            const int e3 = order[i + 3];
            const float xv0 = x[(long long)e0 * EDGE_DIM + lane];
            const float xv1 = x[(long long)e1 * EDGE_DIM + lane];
            const float xv2 = x[(long long)e2 * EDGE_DIM + lane];
            const float xv3 = x[(long long)e3 * EDGE_DIM + lane];
            const float* r0 = rbf + (long long)e0 * 16;
            const float* r1 = rbf + (long long)e1 * 16;
            const float* r2 = rbf + (long long)e2 * 16;
            const float* r3 = rbf + (long long)e3 * 16;
            float s0 = 0.f, s1 = 0.f, s2 = 0.f, s3 = 0.f;
#pragma unroll
            for (int q = 0; q < 16; ++q) {
                s0 = fmaf(r0[q], wreg[q], s0);
                s1 = fmaf(r1[q], wreg[q], s1);
                s2 = fmaf(r2[q], wreg[q], s2);
                s3 = fmaf(r3[q], wreg[q], s3);
            }
            acc = fmaf(s0, xv0, acc);
            acc = fmaf(s1, xv1, acc);
            acc = fmaf(s2, xv2, acc);
            acc = fmaf(s3, xv3, acc);
        }
        for (; i < b1; ++i) {
            const int e = order[i];
            const float xv = x[(long long)e * EDGE_DIM + lane];
            const float* rp = rbf + (long long)e * 16;
            float s = 0.f;
#pragma unroll
            for (int q = 0; q < 16; ++q) s = fmaf(rp[q], wreg[q], s);
            acc = fmaf(s, xv, acc);
        }
        h[(long long)n * EDGE_DIM + lane] = acc;
    }
}

// ---------------------------------------------------------------------------
// Pack all 4 weight matrices into MFMA-fragment bf16 hi/lo order, one launch.
// Fragment (kt,nt): lane l elem j holds W[kt*32 + 8*(l>>4) + j][nt*16+(l&15)].
// ---------------------------------------------------------------------------
__device__ __forceinline__ void pack_body(const float* __restrict__ W,
                                          short* __restrict__ out, int t) {
    int l = t & 63, f = t >> 6;
    int kt = f >> 4, nt = f & 15;
    int kbase = kt * 32 + (l >> 4) * 8;
    int col = nt * 16 + (l & 15);
#pragma unroll
    for (int j = 0; j < 8; ++j) {
        float v = W[(kbase + j) * UPD + col];
        short hb = f2bf(v);
        short lb = f2bf(v - bf2f(hb));
        out[f * 1024 + l * 8 + j] = hb;
        out[f * 1024 + 512 + l * 8 + j] = lb;
    }
}

__global__ __launch_bounds__(256) void pack_all_kernel(
    const float* __restrict__ Wup, const float* __restrict__ W1,
    const float* __restrict__ W2, const float* __restrict__ W3,
    short* __restrict__ oup, short* __restrict__ o1, short* __restrict__ o2,
    short* __restrict__ o3) {
    const int b = blockIdx.x;
    if (b < 8) {  // W_up: 32 frags * 64 lanes / 256 = 8 blocks
        pack_body(Wup, oup, b * 256 + threadIdx.x);
    } else if (b < 40) {
        pack_body(W1, o1, (b - 8) * 256 + threadIdx.x);
    } else if (b < 72) {
        pack_body(W2, o2, (b - 40) * 256 + threadIdx.x);
    } else {
        pack_body(W3, o3, (b - 72) * 256 + threadIdx.x);
    }
}

// ---------------------------------------------------------------------------
// MFMA node MLP (unchanged).
// ---------------------------------------------------------------------------
template <int NK>
__device__ __forceinline__ void mm_layer(const short* AH, const short* AL,
                                         const short* __restrict__ Wpk,
                                         int lr, int lh, int lane, int wq,
                                         f32x4 acc[4][4]) {
#pragma unroll
    for (int kt = 0; kt < NK; ++kt) {
        bf16x8 a[4][2];
#pragma unroll
        for (int m = 0; m < 4; ++m) {
            int r = m * 16 + lr;
            int ch = (kt * 4 + lh) ^ (r & 7);
            int off = r * 256 + ch * 8;  // shorts
            a[m][0] = *(const bf16x8*)(AH + off);
            a[m][1] = *(const bf16x8*)(AL + off);
        }
        bf16x8 b[4][2];
#pragma unroll
        for (int nf = 0; nf < 4; ++nf) {
            int f = kt * 16 + wq * 4 + nf;
            const short* p = Wpk + f * 1024 + lane * 8;
            b[nf][0] = *(const bf16x8*)(p);
            b[nf][1] = *(const bf16x8*)(p + 512);
        }
#pragma unroll
        for (int m = 0; m < 4; ++m)
#pragma unroll
            for (int nf = 0; nf < 4; ++nf) {
                acc[m][nf] = __builtin_amdgcn_mfma_f32_16x16x32_bf16(
                    a[m][0], b[nf][0], acc[m][nf], 0, 0, 0);
                acc[m][nf] = __builtin_amdgcn_mfma_f32_16x16x32_bf16(
                    a[m][0], b[nf][1], acc[m][nf], 0, 0, 0);
                acc[m][nf] = __builtin_amdgcn_mfma_f32_16x16x32_bf16(
                    a[m][1], b[nf][0], acc[m][nf], 0, 0, 0);
            }
    }
}

template <bool ACT>
__device__ __forceinline__ void epilogue_store(f32x4 acc[4][4], short* AH,
                                               short* AL,
                                               const float* __restrict__ bias,
                                               int lr, int lh, int wq) {
    float bv[4] = {0.f, 0.f, 0.f, 0.f};
    if (bias) {
#pragma unroll
        for (int nf = 0; nf < 4; ++nf) bv[nf] = bias[wq * 64 + nf * 16 + lr];
    }
#pragma unroll
    for (int m = 0; m < 4; ++m)
#pragma unroll
        for (int nf = 0; nf < 4; ++nf) {
            int c = wq * 64 + nf * 16 + lr;
#pragma unroll
            for (int reg = 0; reg < 4; ++reg) {
                float v = acc[m][nf][reg] + bv[nf];
                if (ACT) v = v / (1.f + __expf(-v));
                int r = m * 16 + lh * 4 + reg;
                short hb = f2bf(v);
                short lb = f2bf(v - bf2f(hb));
                int off = r * 256 + (((c >> 3) ^ (r & 7)) * 8) + (c & 7);
                AH[off] = hb;
                AL[off] = lb;
            }
        }
}

__global__ __launch_bounds__(256, 2) void node_mlp_mfma(
    const float* __restrict__ h,
    const short* __restrict__ Wup_pk, const short* __restrict__ W1_pk,
    const short* __restrict__ W2_pk, const short* __restrict__ W3_pk,
    const float* __restrict__ b1, const float* __restrict__ b2,
    const float* __restrict__ b3, const float* __restrict__ W_out,
    float* __restrict__ out, int nn) {
    __shared__ short AH[64 * 256];
    __shared__ short AL[64 * 256];
    __shared__ float Bpart[64 * 4];

    const int tid = threadIdx.x;
    const int lane = tid & 63, wq = tid >> 6;
    const int lr = lane & 15, lh = lane >> 4;
    const int node0 = blockIdx.x * 64;

    // Stage h tile (64 x 64 f32) -> hi/lo bf16, swizzled, cols 0..63.
#pragma unroll
    for (int i = 0; i < 4; ++i) {
        int idx4 = tid + i * 256;  // 0..1023 float4s
        int r = idx4 >> 4, c4 = idx4 & 15;
        float4 v = {0.f, 0.f, 0.f, 0.f};
        if (node0 + r < nn)
            v = *(const float4*)(h + (long long)(node0 + r) * EDGE_DIM + c4 * 4);
        short h0 = f2bf(v.x), h1 = f2bf(v.y), h2 = f2bf(v.z), h3 = f2bf(v.w);
        short l0 = f2bf(v.x - bf2f(h0)), l1 = f2bf(v.y - bf2f(h1));
        short l2 = f2bf(v.z - bf2f(h2)), l3 = f2bf(v.w - bf2f(h3));
        int off = r * 256 + (((c4 >> 1) ^ (r & 7)) * 8) + (c4 & 1) * 4;
        uint2 hw, lw;
        hw.x = (unsigned short)h0 | ((unsigned)(unsigned short)h1 << 16);
        hw.y = (unsigned short)h2 | ((unsigned)(unsigned short)h3 << 16);
        lw.x = (unsigned short)l0 | ((unsigned)(unsigned short)l1 << 16);
        lw.y = (unsigned short)l2 | ((unsigned)(unsigned short)l3 << 16);
        *(uint2*)(AH + off) = hw;
        *(uint2*)(AL + off) = lw;
    }
    __syncthreads();

    f32x4 acc[4][4];

    // Layer up: K=64, no bias, no act.
#pragma unroll
    for (int m = 0; m < 4; ++m)
#pragma unroll
        for (int n = 0; n < 4; ++n) acc[m][n] = (f32x4){0.f, 0.f, 0.f, 0.f};
    mm_layer<2>(AH, AL, Wup_pk, lr, lh, lane, wq, acc);
    __syncthreads();
    epilogue_store<false>(acc, AH, AL, nullptr, lr, lh, wq);
    __syncthreads();

    // Layer 1
#pragma unroll
    for (int m = 0; m < 4; ++m)
#pragma unroll
        for (int n = 0; n < 4; ++n) acc[m][n] = (f32x4){0.f, 0.f, 0.f, 0.f};
    mm_layer<8>(AH, AL, W1_pk, lr, lh, lane, wq, acc);
    __syncthreads();
    epilogue_store<true>(acc, AH, AL, b1, lr, lh, wq);
    __syncthreads();

    // Layer 2
#pragma unroll
    for (int m = 0; m < 4; ++m)
#pragma unroll
        for (int n = 0; n < 4; ++n) acc[m][n] = (f32x4){0.f, 0.f, 0.f, 0.f};
    mm_layer<8>(AH, AL, W2_pk, lr, lh, lane, wq, acc);
    __syncthreads();
    epilogue_store<true>(acc, AH, AL, b2, lr, lh, wq);
    __syncthreads();

    // Layer 3 + fused head: out = silu(acc + b3) . W_out
#pragma unroll
    for (int m = 0; m < 4; ++m)
#pragma unroll
        for (int n = 0; n < 4; ++n) acc[m][n] = (f32x4){0.f, 0.f, 0.f, 0.f};
    mm_layer<8>(AH, AL, W3_pk, lr, lh, lane, wq, acc);

    float b3v[4], wo[4];
#pragma unroll
    for (int nf = 0; nf < 4; ++nf) {
        int c = wq * 64 + nf * 16 + lr;
        b3v[nf] = b3[c];
        wo[nf] = W_out[c];
    }
#pragma unroll
    for (int m = 0; m < 4; ++m) {
#pragma unroll
        for (int reg = 0; reg < 4; ++reg) {
            float s = 0.f;
#pragma unroll
            for (int nf = 0; nf < 4; ++nf) {
                float v = acc[m][nf][reg] + b3v[nf];
                v = v / (1.f + __expf(-v));
                s = fmaf(v, wo[nf], s);
            }
            s += __shfl_xor(s, 1);
            s += __shfl_xor(s, 2);
            s += __shfl_xor(s, 4);
            s += __shfl_xor(s, 8);
            if (lr == 0) Bpart[(m * 16 + lh * 4 + reg) * 4 + wq] = s;
        }
    }
    __syncthreads();
    if (tid < 64) {
        float s = Bpart[tid * 4] + Bpart[tid * 4 + 1] + Bpart[tid * 4 + 2] +
                  Bpart[tid * 4 + 3];
        if (node0 + tid < nn) out[node0 + tid] = s;
    }
}

// ---------------------------------------------------------------------------
extern "C" void kernel_launch(void* const* d_in, const int* in_sizes, int n_in,
                              void* d_out, int out_size, void* d_ws, size_t ws_size,
                              hipStream_t stream) {
    const float* x     = (const float*)d_in[0];
    const float* rbf   = (const float*)d_in[1];
    const void*  idx   = d_in[2];
    const float* W_rbf = (const float*)d_in[4];
    const float* W_up  = (const float*)d_in[5];
    const float* W1    = (const float*)d_in[6];
    const float* b1    = (const float*)d_in[7];
    const float* W2    = (const float*)d_in[8];
    const float* b2    = (const float*)d_in[9];
    const float* W3    = (const float*)d_in[10];
    const float* b3    = (const float*)d_in[11];
    const float* W_out = (const float*)d_in[12];
    float* out = (float*)d_out;

    const int n_edge = in_sizes[0] / EDGE_DIM;
    const int nn = out_size;

    // Workspace layout
    char* p = (char*)d_ws;
    float* h = (float*)p;            p += (size_t)nn * EDGE_DIM * sizeof(float);
    short* wup_pk = (short*)p;       p += 32 * 1024 * sizeof(short);
    short* w1_pk = (short*)p;        p += 128 * 1024 * sizeof(short);
    short* w2_pk = (short*)p;        p += 128 * 1024 * sizeof(short);
    short* w3_pk = (short*)p;        p += 128 * 1024 * sizeof(short);
    int* count = (int*)p;            p += (size_t)nn * sizeof(int);
    int* base = (int*)p;             p += (size_t)(nn + 1) * sizeof(int);
    int* cursor = (int*)p;           p += (size_t)nn * sizeof(int);
    int* partial = (int*)p;          p += 256 * sizeof(int);
    int* order = (int*)p;

    const int nblk_scan = (nn + 1023) / 1024;

    hipMemsetAsync(count, 0, (size_t)nn * sizeof(int), stream);
    pack_all_kernel<<<104, 256, 0, stream>>>(W_up, W1, W2, W3, wup_pk, w1_pk,
                                             w2_pk, w3_pk);
    count_kernel<<<2048, 256, 0, stream>>>(idx, n_edge, nn, count);
    scan_a<<<nblk_scan, 256, 0, stream>>>(count, base, partial, nn);
    scan_b<<<1, 256, 0, stream>>>(partial, nblk_scan);
    scan_c<<<nblk_scan, 256, 0, stream>>>(base, cursor, partial, nn, n_edge);
    fill_order_kernel<<<2048, 256, 0, stream>>>(idx, n_edge, nn, cursor,
                                                order);
    gather_kernel<<<4096, 256, 0, stream>>>(x, rbf, order, base, W_rbf, h, nn);

    const int nb = (nn + 63) / 64;
    node_mlp_mfma<<<nb, 256, 0, stream>>>(h, wup_pk, w1_pk, w2_pk, w3_pk,
                                          b1, b2, b3, W_out, out, nn);
}